// Round 12
// baseline (365.647 us; speedup 1.0000x reference)
//
#include <hip/hip_runtime.h>

#define USH unsigned short

// ---------- bf16 helpers (storage = unsigned short) ----------
__device__ __forceinline__ float b2f(USH u) {
    union { unsigned int i; float f; } x; x.i = ((unsigned int)u) << 16; return x.f;
}
__device__ __forceinline__ USH f2b(float f) {
    union { float f; unsigned int i; } x; x.f = f;
    unsigned int r = x.i + (0x7fffu + ((x.i >> 16) & 1u));  // RNE
    return (USH)(r >> 16);
}
__device__ __forceinline__ float ldf(const USH* p)  { return b2f(*p); }
__device__ __forceinline__ float ldf(const float* p){ return *p; }
__device__ __forceinline__ void stf(USH* p, float v)  { *p = f2b(v); }
__device__ __forceinline__ void stf(float* p, float v){ *p = v; }

// async global->LDS, 16B per lane (dest = wave-uniform base + lane*16)
#define GLOAD16(gp, lp) __builtin_amdgcn_global_load_lds(                     \
    (const __attribute__((address_space(1))) void*)(gp),                      \
    (__attribute__((address_space(3))) void*)(lp), 16, 0, 0)

typedef __attribute__((ext_vector_type(8)))  __bf16 bf16x8;
typedef __attribute__((ext_vector_type(4)))  float  floatx4;
typedef __attribute__((ext_vector_type(16))) float  floatx16;

// =====================================================================
// Weight transpose+convert: W[K][N] f32 -> WT[N][K] bf16.
// =====================================================================
__global__ __launch_bounds__(256) void transpose_f2b(const float* __restrict__ W,
                                                     USH* __restrict__ WT,
                                                     int K, int N) {
    __shared__ USH t[64][72];
    int n0 = blockIdx.x * 64, k0 = blockIdx.y * 64;
    int tid = threadIdx.x;
    int kr = tid >> 4, nc = (tid & 15) * 4;
#pragma unroll
    for (int r = 0; r < 4; r++) {
        int k = kr + r * 16;
        float4 v = *(const float4*)(W + (size_t)(k0 + k) * N + n0 + nc);
        t[nc + 0][k] = f2b(v.x); t[nc + 1][k] = f2b(v.y);
        t[nc + 2][k] = f2b(v.z); t[nc + 3][k] = f2b(v.w);
    }
    __syncthreads();
    int nr = tid >> 2, kc = (tid & 3) * 8;
#pragma unroll
    for (int r = 0; r < 2; r++) {
        int k = kc + r * 32;
        *(int4*)(WT + (size_t)(n0 + nr) * K + k0 + k) = *(const int4*)&t[nr][k];
    }
}

// =====================================================================
// LayerNorm rows of 1024. block=256, one block/row.
// =====================================================================
template <typename TX>
__global__ __launch_bounds__(256) void ln_rows(const TX* __restrict__ x,
                                               const float* __restrict__ g,
                                               const float* __restrict__ bb,
                                               USH* __restrict__ y) {
    int row = blockIdx.x, tid = threadIdx.x;
    const TX* xr = x + (size_t)row * 1024 + tid * 4;
    float v[4];
#pragma unroll
    for (int i = 0; i < 4; i++) v[i] = ldf(xr + i);
    float s  = v[0] + v[1] + v[2] + v[3];
    float ss = v[0]*v[0] + v[1]*v[1] + v[2]*v[2] + v[3]*v[3];
#pragma unroll
    for (int o = 32; o; o >>= 1) { s += __shfl_down(s, o); ss += __shfl_down(ss, o); }
    __shared__ float red[10];
    int w = tid >> 6;
    if ((tid & 63) == 0) { red[w] = s; red[4 + w] = ss; }
    __syncthreads();
    if (tid == 0) {
        float S = red[0] + red[1] + red[2] + red[3];
        float SS = red[4] + red[5] + red[6] + red[7];
        float mean = S * (1.f / 1024.f);
        float var  = SS * (1.f / 1024.f) - mean * mean;
        red[8] = mean; red[9] = rsqrtf(var + 1e-5f);
    }
    __syncthreads();
    float mean = red[8], rstd = red[9];
    USH* yr = y + (size_t)row * 1024 + tid * 4;
#pragma unroll
    for (int i = 0; i < 4; i++) {
        int c = tid * 4 + i;
        yr[i] = f2b((v[i] - mean) * rstd * g[c] + bb[c]);
    }
}

// =====================================================================
// zh = z @ wca + bca, emitting packed MFMA operand rows (head-major),
// exp2-domain fold (gvl = softplus(gamma)*log2e).
// =====================================================================
__global__ __launch_bounds__(256) void zh_kernel(const float* __restrict__ z,
                                                 const float* __restrict__ wca,
                                                 const float* __restrict__ bca,
                                                 const float* __restrict__ gamma,
                                                 USH* __restrict__ zq_pack,
                                                 USH* __restrict__ zk_pack) {
    int row = blockIdx.x, n = threadIdx.x;
    __shared__ float zrow[64];
    if (n < 64) zrow[n] = z[(size_t)row * 64 + n];
    __syncthreads();
    float s = bca[n];
#pragma unroll 8
    for (int k = 0; k < 64; k++) s = fmaf(zrow[k], wca[(size_t)k * 256 + n], s);
    int h = n >> 4, c = n & 15;
    float gvl = log1pf(__expf(gamma[h])) * 1.44269504f;  // softplus * log2e
    USH u = f2b(s);
    float sv = b2f(u);
    float sq = sv * sv;
    sq += __shfl_xor(sq, 1); sq += __shfl_xor(sq, 2);
    sq += __shfl_xor(sq, 4); sq += __shfl_xor(sq, 8);
    size_t base = ((size_t)h * 4096 + row) * 32;
    zk_pack[base + c] = u;
    zq_pack[base + c] = f2b(2.f * gvl * s);
    if (c == 0) {
        USH hi = f2b(sq);
        float lo = sq - b2f(hi);
        unsigned int kw0 = 0x3F80u | ((unsigned int)hi << 16);
        unsigned int kw1 = (unsigned int)f2b(lo);
        uint4 kv = {kw0, kw1, 0u, 0u};
        uint4 zz = {0u, 0u, 0u, 0u};
        *(uint4*)(zk_pack + base + 16) = kv;
        *(uint4*)(zk_pack + base + 24) = zz;
        unsigned int qw0 = (unsigned int)f2b(-gvl * sq) | ((unsigned int)f2b(-gvl) << 16);
        unsigned int qw1 = (unsigned int)f2b(-gvl);
        uint4 qv = {qw0, qw1, 0u, 0u};
        *(uint4*)(zq_pack + base + 16) = qv;
        *(uint4*)(zq_pack + base + 24) = zz;
    }
}

// =====================================================================
// MFMA GEMM v6: templated BK (64 or 128), XOR-swizzled gload_lds staging.
// KB=128 for the grid-capped N=1024 GEMMs; KB=64 for FFN1 (occupancy).
// EPI: 0 = plain | 1 = +res | 2 = gelu | 3 = +res
// =====================================================================
template <int EPI, int MI, int NI, int KB, typename TRES, typename TOUT>
__global__ __launch_bounds__(256) void gemm_kernel(const USH* __restrict__ A,
                                                   const USH* __restrict__ WT,
                                                   const float* __restrict__ bias,
                                                   const TRES* __restrict__ res,
                                                   TOUT* __restrict__ out,
                                                   int M, int N, int K) {
    constexpr int BM  = MI * 32;
    constexpr int BN  = NI * 32;
    constexpr int GR  = KB / 8;        // 16B granules per row
    constexpr int RPC = 2048 / KB;     // rows per 4KB staged chunk
    constexpr int ACH = BM / RPC;      // A chunks per K-step
    constexpr int BCH = BN / RPC;      // B chunks per K-step
    __shared__ __align__(16) USH lA[BM][KB];
    __shared__ __align__(16) USH lB[BN][KB];
    int tid = threadIdx.x;
    int lane = tid & 63, wave = tid >> 6;
    int wr = wave >> 1, wc = wave & 1;
    int quad = lane >> 4, l15 = lane & 15;
    int m0 = blockIdx.x * BM, n0 = blockIdx.y * BN;

    int srow = tid / GR;               // row within chunk
    int kg   = tid % GR;               // 16B granule within row
    int scol = (kg ^ (srow & 7)) * 8;  // swizzled source column

    const USH* gA = A + (size_t)(m0 + srow) * K + scol;
    const USH* gB = WT + (size_t)(n0 + srow) * K + scol;
    USH* lA0 = &lA[0][0] + tid * 8;    // lane*16B dest (linear)
    USH* lB0 = &lB[0][0] + tid * 8;
    int xo = (l15 & 7) * 8;            // read-side XOR

    floatx4 acc[MI][NI] = {};

    for (int k0 = 0; k0 < K; k0 += KB) {
#pragma unroll
        for (int c = 0; c < ACH; c++)
            GLOAD16(gA + (size_t)c * RPC * K + k0, lA0 + c * 2048);
#pragma unroll
        for (int c = 0; c < BCH; c++)
            GLOAD16(gB + (size_t)c * RPC * K + k0, lB0 + c * 2048);
        __syncthreads();

#pragma unroll
        for (int ks = 0; ks < KB / 32; ks++) {
            bf16x8 bfr[NI];
#pragma unroll
            for (int ni = 0; ni < NI; ni++)
                bfr[ni] = *(const bf16x8*)&lB[wc * (NI * 16) + ni * 16 + l15][(ks * 32 + quad * 8) ^ xo];
#pragma unroll
            for (int mi = 0; mi < MI; mi++) {
                bf16x8 afr = *(const bf16x8*)&lA[wr * (MI * 16) + mi * 16 + l15][(ks * 32 + quad * 8) ^ xo];
#pragma unroll
                for (int ni = 0; ni < NI; ni++)
                    acc[mi][ni] = __builtin_amdgcn_mfma_f32_16x16x32_bf16(afr, bfr[ni], acc[mi][ni], 0, 0, 0);
            }
        }
        __syncthreads();
    }

    float bias_v[NI];
#pragma unroll
    for (int ni = 0; ni < NI; ni++) bias_v[ni] = bias[n0 + wc * (NI * 16) + ni * 16 + l15];

#pragma unroll
    for (int mi = 0; mi < MI; mi++) {
#pragma unroll
        for (int r = 0; r < 4; r++) {
            int row = m0 + wr * (MI * 16) + mi * 16 + quad * 4 + r;
            size_t base = (size_t)row * N;
#pragma unroll
            for (int ni = 0; ni < NI; ni++) {
                int col = n0 + wc * (NI * 16) + ni * 16 + l15;
                float v = acc[mi][ni][r] + bias_v[ni];
                if (EPI == 2) {
                    // tanh-form GELU: v * sigmoid(1.5958*v + 0.07135*v^3)
                    float t = v * v;
                    float a = fmaf(t, -0.0713548162726f, -1.59576912161f);
                    v = v * __builtin_amdgcn_rcpf(1.f + __expf(v * a));
                }
                if (EPI == 1 || EPI == 3) v += ldf(res + base + col);
                stf(out + base + col, v);
            }
        }
    }
}

// =====================================================================
// Flash distance-attention v16: 32x32x16 MFMA (LDS-traffic halving).
// Diagnosis (R11): kernel is LDS-pipe-bound (~31 µs b128 reads + ~10 µs
// staging writes + 11 µs conflicts in 61.7 µs; MFMA only ~14.5 µs).
// 16x16x32 reads 32 B/lane per 256 FLOP/lane; 32x32x16 reads 32 B per
// 512 FLOP -> LDS bytes per FLOP HALVED.
// Structure: 8 waves = 4 q-chunks (32 rows) x 2 key-groups (32 of each
// 64-key tile). Per wave per tile: 2 QK + 4 PV + 2 rowsum MFMA (32x32),
// 6 b128 LDS reads (was 12). Same total FLOPs/barriers; one 3-round
// LDS merge of key-group partials at the end.
// Layouts (from HW-verified 32x32 C/D map m74/m101 + A/B lane rule
// validated by the working 16x16 kernels):
//  - A: lane holds A[row=l&31][k=(l>>5)*8+j]; B: B[k=(l>>5)*8+j][col=l&31]
//  - swapped QK: sacc[reg] = S[key=(reg&3)+8*(reg>>2)+4*(l>>5)][q=l&31]
//  - PV A-operand: ap[m] elem j = exp2(sacc[m*8+j]) under V key-perm
//    sigma(K) = 16*((K>>4)&1) + 8*((K>>2)&1) + 4*((K>>3)&1) + (K&3)
//    per 32-key group (keys 4k..4k+3 -> 4 adjacent slots -> b64 writes).
//  - V staging: thread (kp=tid>>4, dhc=tid&15): keys 4kp..+3, dh rows
//    {2dhc,2dhc+1,2dhc+32,2dhc+33}; write banks (8dhc+4e'+cb)%32 = all
//    even starts x4 lanes = conflict-free b64 minimum.
// LDS 28 KB (+20 KB merge overlay of the dead K/V buffers).
// =====================================================================
__global__ __launch_bounds__(512, 4) void attn16_kernel(const USH* __restrict__ zq_pack,
                                                        const USH* __restrict__ zk_pack,
                                                        const USH* __restrict__ value,
                                                        USH* __restrict__ attn_out) {
    int b = blockIdx.x >> 4, h = blockIdx.x & 15;
    int q0 = blockIdx.y * 128;
    int tid = threadIdx.x, lane = tid & 63, wq = tid >> 6;   // wq 0..7
    int qc = wq & 3, kg = wq >> 2;        // q-chunk / key-group
    int l31 = lane & 31, lh = lane >> 5;  // half-select

    __shared__ __align__(16) char smem[28672];
    typedef USH KbT_t[64][40];            // 10240 B (x2 buf)
    typedef USH VbT_t[64][72];            // 18432 B (x2 buf)
    KbT_t* KbT = reinterpret_cast<KbT_t*>(smem);
    VbT_t* VbT = reinterpret_cast<VbT_t*>(smem + 10240);
    float (*mrg)[64][20] = reinterpret_cast<float(*)[64][20]>(smem);  // overlay

    const size_t zrow0 = (size_t)b * 2048;
    const USH* zq = zq_pack + ((size_t)h * 4096 + zrow0) * 32;
    const USH* zk = zk_pack + ((size_t)h * 4096 + zrow0) * 32;
    const size_t vbase = zrow0 * 1024 + h * 64;

    // Q fragments (B-operand), two k-halves, direct from global
    bf16x8 qf0 = *(const bf16x8*)(zq + (size_t)(q0 + qc * 32 + l31) * 32 + lh * 8);
    bf16x8 qf1 = *(const bf16x8*)(zq + (size_t)(q0 + qc * 32 + l31) * 32 + 16 + lh * 8);

    // ones fragment (bf16 1.0 x8)
    union { unsigned int u[4]; bf16x8 v; } onesu;
#pragma unroll
    for (int i = 0; i < 4; i++) onesu.u[i] = 0x3F803F80u;
    bf16x8 ones = onesu.v;

    floatx16 oacc0 = {}, oacc1 = {}, lacc = {};

    // staging roles: tid<256 -> V loader; tid>=256 -> K loader
    int kp   = tid >> 4;                  // 0..15 (V role)
    int dhc  = tid & 15;
    int key0 = kp * 4;
    int cb   = (kp >> 3) * 32 + ((kp >> 2) & 1) * 16 + (kp & 1) * 8 + ((kp >> 1) & 1) * 4;
    int krow = (tid - 256) >> 2, kc0 = ((tid - 256) & 3) * 8;
    unsigned int vlo[4], vhi[4]; uint4 kreg;

#define VLOAD(ktv) do {                                                        \
        const USH* s_ = value + vbase + (size_t)((ktv) + key0) * 1024 + dhc * 2; \
        _Pragma("unroll")                                                      \
        for (int i_ = 0; i_ < 4; i_++) {                                       \
            vlo[i_] = *(const unsigned int*)(s_ + (size_t)i_ * 1024);          \
            vhi[i_] = *(const unsigned int*)(s_ + (size_t)i_ * 1024 + 32);     \
        } } while (0)

#define VWRITE(bufv) do {                                                      \
        uint2 w_;                                                              \
        w_.x = (vlo[0] & 0xFFFFu) | (vlo[1] << 16);                            \
        w_.y = (vlo[2] & 0xFFFFu) | (vlo[3] << 16);                            \
        *(uint2*)&VbT[bufv][2 * dhc][cb] = w_;                                 \
        w_.x = (vlo[0] >> 16) | (vlo[1] & 0xFFFF0000u);                        \
        w_.y = (vlo[2] >> 16) | (vlo[3] & 0xFFFF0000u);                        \
        *(uint2*)&VbT[bufv][2 * dhc + 1][cb] = w_;                             \
        w_.x = (vhi[0] & 0xFFFFu) | (vhi[1] << 16);                            \
        w_.y = (vhi[2] & 0xFFFFu) | (vhi[3] << 16);                            \
        *(uint2*)&VbT[bufv][2 * dhc + 32][cb] = w_;                            \
        w_.x = (vhi[0] >> 16) | (vhi[1] & 0xFFFF0000u);                        \
        w_.y = (vhi[2] >> 16) | (vhi[3] & 0xFFFF0000u);                        \
        *(uint2*)&VbT[bufv][2 * dhc + 33][cb] = w_;                            \
    } while (0)

    // ---- prologue: tile 0 -> LDS buf0; tile 1 -> regs ----
    if (tid < 256) {
        VLOAD(0);
        VWRITE(0);
        VLOAD(64);
    } else {
        kreg = *(const uint4*)(zk + (size_t)krow * 32 + kc0);
        *(uint4*)&KbT[0][krow][kc0] = kreg;
        kreg = *(const uint4*)(zk + (size_t)(64 + krow) * 32 + kc0);
    }

    for (int it = 0; it < 32; it++) {
        int cur = it & 1;
        __syncthreads();   // tile `it` staged; prev tile's reads done
        // ---- write tile it+1 into buf^1; issue loads for tile it+2 ----
        if (it + 1 < 32) {
            if (tid < 256) {
                VWRITE(cur ^ 1);
                if (it + 2 < 32) VLOAD((it + 2) * 64);
            } else {
                *(uint4*)&KbT[cur ^ 1][krow][kc0] = kreg;
                if (it + 2 < 32)
                    kreg = *(const uint4*)(zk + (size_t)((it + 2) * 64 + krow) * 32 + kc0);
            }
        }

        // ---- QK^T (swapped, 32x32x16): sacc[key-slice][q] ----
        bf16x8 kf0 = *(const bf16x8*)&KbT[cur][kg * 32 + l31][lh * 8];
        bf16x8 kf1 = *(const bf16x8*)&KbT[cur][kg * 32 + l31][16 + lh * 8];
        floatx16 zz = {};
        floatx16 sacc = __builtin_amdgcn_mfma_f32_32x32x16_bf16(kf0, qf0, zz, 0, 0, 0);
        sacc = __builtin_amdgcn_mfma_f32_32x32x16_bf16(kf1, qf1, sacc, 0, 0, 0);

        // ---- exp2 + in-register P pack (A-fragment under sigma) ----
        bf16x8 ap[2];
#pragma unroll
        for (int m = 0; m < 2; m++) {
            union { unsigned int u[4]; bf16x8 v; } pu;
#pragma unroll
            for (int d = 0; d < 4; d++) {
                union { float f; unsigned int i; } a, c;
                a.f = exp2f(sacc[m * 8 + 2 * d + 0]);
                c.f = exp2f(sacc[m * 8 + 2 * d + 1]);
                pu.u[d] = (a.i >> 16) | (c.i & 0xFFFF0000u);
            }
            ap[m] = pu.v;
        }

        // ---- PV + rowsum (K=16 per MFMA, 2 MFMA over this wave's 32 keys)
#pragma unroll
        for (int m = 0; m < 2; m++) {
            bf16x8 bv0 = *(const bf16x8*)&VbT[cur][l31][kg * 32 + m * 16 + lh * 8];
            bf16x8 bv1 = *(const bf16x8*)&VbT[cur][32 + l31][kg * 32 + m * 16 + lh * 8];
            oacc0 = __builtin_amdgcn_mfma_f32_32x32x16_bf16(ap[m], bv0, oacc0, 0, 0, 0);
            oacc1 = __builtin_amdgcn_mfma_f32_32x32x16_bf16(ap[m], bv1, oacc1, 0, 0, 0);
            lacc  = __builtin_amdgcn_mfma_f32_32x32x16_bf16(ap[m], ones, lacc, 0, 0, 0);
        }
    }
#undef VLOAD
#undef VWRITE

    // ---- merge key-group partials (kg=1 -> LDS -> kg=0 adds), 3 rounds
    __syncthreads();                     // all K/V buffer reads complete
    if (kg == 1) {
#pragma unroll
        for (int r = 0; r < 16; r++) mrg[qc][lane][r] = oacc0[r];
    }
    __syncthreads();
    if (kg == 0) {
#pragma unroll
        for (int r = 0; r < 16; r++) oacc0[r] += mrg[qc][lane][r];
    }
    __syncthreads();
    if (kg == 1) {
#pragma unroll
        for (int r = 0; r < 16; r++) mrg[qc][lane][r] = oacc1[r];
    }
    __syncthreads();
    if (kg == 0) {
#pragma unroll
        for (int r = 0; r < 16; r++) oacc1[r] += mrg[qc][lane][r];
    }
    __syncthreads();
    if (kg == 1) {
#pragma unroll
        for (int r = 0; r < 16; r++) mrg[qc][lane][r] = lacc[r];
    }
    __syncthreads();

    if (kg == 0) {
#pragma unroll
        for (int r = 0; r < 16; r++) {
            float inv = 1.f / (lacc[r] + mrg[qc][lane][r]);
            int row = q0 + qc * 32 + (r & 3) + 8 * (r >> 2) + 4 * lh;
            USH* o = attn_out + (zrow0 + row) * 1024 + h * 64 + l31;
            o[0]  = f2b(oacc0[r] * inv);
            o[32] = f2b(oacc1[r] * inv);
        }
    }
}

// =====================================================================
// z_out = LN(z + z_next) over rows of 64. block = 64 (one wave) per row.
// =====================================================================
__global__ __launch_bounds__(64) void lnc_kernel(const float* __restrict__ z,
                                                 const float* __restrict__ zn,
                                                 const float* __restrict__ g,
                                                 const float* __restrict__ bb,
                                                 float* __restrict__ out) {
    int row = blockIdx.x, t = threadIdx.x;
    float v = z[(size_t)row * 64 + t] + zn[(size_t)row * 64 + t];
    float s = v, ss = v * v;
#pragma unroll
    for (int o = 32; o; o >>= 1) { s += __shfl_xor(s, o); ss += __shfl_xor(ss, o); }
    float mean = s * (1.f / 64.f);
    float rstd = rsqrtf(ss * (1.f / 64.f) - mean * mean + 1e-5f);
    out[(size_t)row * 64 + t] = (v - mean) * rstd * g[t] + bb[t];
}

// =====================================================================
extern "C" void kernel_launch(void* const* d_in, const int* in_sizes, int n_in,
                              void* d_out, int out_size, void* d_ws, size_t ws_size,
                              hipStream_t stream) {
    // workspace layout (61 MB):
    //   [0,8M)    value    [8,16M) attn_o    [16,20M) zq_pack
    //   [20,24M)  zk_pack  [24,32M) hn
    //   [0,32M)   mid (overlays, written step 8)
    //   [32,40M)  hn2   [40,41M) znext
    //   [41,43M)  wvT  [43,45M) woT  [45,53M) w1T  [53,61M) w2T
    //   wcnT (128K) borrows the head of attn_o: written step 0, read
    //   step 4, overwritten step 5.
    // h1 (f32) lives in d_out's h region.
    char* p = (char*)d_ws;
    USH*   value   = (USH*)(p);
    USH*   attn_o  = (USH*)(p + ((size_t)8  << 20));
    USH*   wcnT    = (USH*)(p + ((size_t)8  << 20));   // overlay, pre-step-5
    USH*   zq_pack = (USH*)(p + ((size_t)16 << 20));
    USH*   zk_pack = (USH*)(p + ((size_t)20 << 20));
    USH*   hn      = (USH*)(p + ((size_t)24 << 20));
    USH*   mid     = (USH*)(p);
    USH*   hn2     = (USH*)(p + ((size_t)32 << 20));
    float* znext   = (float*)(p + ((size_t)40 << 20));
    USH*   wvT     = (USH*)(p + ((size_t)41 << 20));
    USH*   woT     = (USH*)(p + ((size_t)43 << 20));
    USH*   w1T     = (USH*)(p + ((size_t)45 << 20));
    USH*   w2T     = (USH*)(p + ((size_t)53 << 20));

    const float *h    = (const float*)d_in[0],  *z    = (const float*)d_in[1];
    const float *wv   = (const float*)d_in[2],  *bv   = (const float*)d_in[3];
    const float *wca  = (const float*)d_in[4],  *bca  = (const float*)d_in[5];
    const float *wcn  = (const float*)d_in[6],  *bcn  = (const float*)d_in[7];
    const float *wo   = (const float*)d_in[8],  *bo   = (const float*)d_in[9];
    const float *gam  = (const float*)d_in[10];
    const float *w1   = (const float*)d_in[11], *b1   = (const float*)d_in[12];
    const float *w2   = (const float*)d_in[13], *b2   = (const float*)d_in[14];
    const float *ln1g = (const float*)d_in[15], *ln1b = (const float*)d_in[16];
    const float *ln2g = (const float*)d_in[17], *ln2b = (const float*)d_in[18];
    const float *lncg = (const float*)d_in[19], *lncb = (const float*)d_in[20];

    float* out_h = (float*)d_out;
    float* out_z = out_h + (size_t)4096 * 1024;
    float* h1    = out_h;

    // 0. weight conversion (f32 [K][N] -> bf16 [N][K])
    transpose_f2b<<<dim3(16, 16), 256, 0, stream>>>(wv, wvT, 1024, 1024);
    transpose_f2b<<<dim3(16, 16), 256, 0, stream>>>(wo, woT, 1024, 1024);
    transpose_f2b<<<dim3(64, 16), 256, 0, stream>>>(w1, w1T, 1024, 4096);
    transpose_f2b<<<dim3(16, 64), 256, 0, stream>>>(w2, w2T, 4096, 1024);
    transpose_f2b<<<dim3(1, 16),  256, 0, stream>>>(wcn, wcnT, 1024, 64);

    // 1. hn = LN1(h)
    ln_rows<float><<<4096, 256, 0, stream>>>(h, ln1g, ln1b, hn);
    // 2. packed attention operands from z (exp2-domain)
    zh_kernel<<<4096, 256, 0, stream>>>(z, wca, bca, gam, zq_pack, zk_pack);
    // 3. value = hn @ wv + bv           (128x64 tiles, BK=128, 512 blocks)
    gemm_kernel<0, 4, 2, 128, USH, USH><<<dim3(32, 16), 256, 0, stream>>>(hn, wvT, bv, (const USH*)nullptr, value, 4096, 1024, 1024);
    // 4. z_next = hn @ wcn + bcn        (MFMA, 32x32 tiles, 256 blocks)
    gemm_kernel<0, 1, 1, 64, float, float><<<dim3(128, 2), 256, 0, stream>>>(hn, wcnT, bcn, (const float*)nullptr, znext, 4096, 64, 1024);
    // 5. attention (32x32 MFMA, register-P, q x key wave split)
    attn16_kernel<<<dim3(32, 16), 512, 0, stream>>>(zq_pack, zk_pack, value, attn_o);
    // 6. h1 = h + attn_o @ wo + bo      (128x64, BK=128, out f32 -> d_out)
    gemm_kernel<1, 4, 2, 128, float, float><<<dim3(32, 16), 256, 0, stream>>>(attn_o, woT, bo, h, h1, 4096, 1024, 1024);
    // 7. hn2 = LN2(h1)
    ln_rows<float><<<4096, 256, 0, stream>>>(h1, ln2g, ln2b, hn2);
    // 8. mid = gelu(hn2 @ w1 + b1)      (128x128, BK=64, 1024 blocks 4/CU)
    gemm_kernel<2, 4, 4, 64, USH, USH><<<dim3(32, 32), 256, 0, stream>>>(hn2, w1T, b1, (const USH*)nullptr, mid, 4096, 4096, 1024);
    // 9. out_h = h1 + mid @ w2 + b2     (128x64, BK=128, res==out same-thread)
    gemm_kernel<3, 4, 2, 128, float, float><<<dim3(32, 16), 256, 0, stream>>>(mid, w2T, b2, h1, out_h, 4096, 1024, 4096);
    // 10. out_z = LN(z + znext)
    lnc_kernel<<<4096, 64, 0, stream>>>(z, znext, lncg, lncb, out_z);
}